// Round 1
// baseline (1306.217 us; speedup 1.0000x reference)
//
#include <hip/hip_runtime.h>
#include <hip/hip_bf16.h>

typedef __attribute__((ext_vector_type(8))) short s16x8;
typedef __attribute__((ext_vector_type(4))) float f32x4;
typedef unsigned short u16;
typedef unsigned int u32;
typedef unsigned long long u64;

#define MFMA(a,b,c) __builtin_amdgcn_mfma_f32_16x16x32_bf16(a,b,c,0,0,0)

constexpr int B_ = 4, T_ = 2048, TKV_ = 512, D_ = 1024, H_ = 16, HD_ = 64;
constexpr int HID_ = 2736, HIDP_ = 2816; // padded to 22*128

__device__ __forceinline__ float bf2f(u16 x) {
    union { float f; u32 u; } c; c.u = ((u32)x) << 16; return c.f;
}
__device__ __forceinline__ u16 f2bf(float f) {
    union { float f; u32 u; } c; c.f = f;
    u32 r = c.u + 0x7fffu + ((c.u >> 16) & 1u);
    return (u16)(r >> 16);
}

__device__ __forceinline__ void gload16(const void* g, void* l) {
    __builtin_amdgcn_global_load_lds(
        (const __attribute__((address_space(1))) u32*)g,
        (__attribute__((address_space(3))) u32*)l, 16, 0, 0);
}

// ---------------- weight transpose + cast:  W[K,N] f32 -> WT[Np,Kp] bf16 (zero-padded)
__global__ __launch_bounds__(256) void wt_cast(const float* __restrict__ W, u16* __restrict__ WT,
                                               int K, int N, int Kp, int Np) {
    __shared__ float t[32][33];
    int tid = threadIdx.x;
    int tx = tid & 31, ty = tid >> 5;
    int n0 = blockIdx.x * 32, k0 = blockIdx.y * 32;
#pragma unroll
    for (int i = 0; i < 4; ++i) {
        int kk = k0 + ty + i * 8, nn = n0 + tx;
        t[ty + i * 8][tx] = (kk < K && nn < N) ? W[(size_t)kk * N + nn] : 0.f;
    }
    __syncthreads();
#pragma unroll
    for (int i = 0; i < 4; ++i) {
        int nn = n0 + ty + i * 8, kk = k0 + tx;
        WT[(size_t)nn * Kp + kk] = f2bf(t[tx][ty + i * 8]);
    }
}

// ---------------- f32 -> bf16 cast (4 elems/thread)
__global__ __launch_bounds__(256) void cast_bf16(const float* __restrict__ in, u16* __restrict__ out, int n4) {
    int i = blockIdx.x * 256 + threadIdx.x;
    if (i >= n4) return;
    float4 v = ((const float4*)in)[i];
    u64 pk = (u64)f2bf(v.x) | ((u64)f2bf(v.y) << 16) | ((u64)f2bf(v.z) << 32) | ((u64)f2bf(v.w) << 48);
    ((u64*)out)[i] = pk;
}

// ---------------- GEMM: C[M,N] = A[M,K] @ Bt[N,K]^T, bf16 in, f32 acc.
// mode 0: f32 out; 1: bf16 out; 2: bf16 silu(out); 3: bf16 out*mul[idx]
__global__ __launch_bounds__(256) void gemm_bf16(const u16* __restrict__ A, const u16* __restrict__ Bt,
                                                 void* __restrict__ C, const u16* __restrict__ mul,
                                                 int M, int N, int K, int mode) {
    __shared__ __align__(16) u16 As[128 * 64];
    __shared__ __align__(16) u16 Bs[128 * 64];
    const int tid = threadIdx.x;
    const int lane = tid & 63, wid = tid >> 6;
    const int wr = wid >> 1, wc = wid & 1;
    const int li = lane & 15, g = lane >> 4;
    const int tn = N >> 7;
    const int m0 = (blockIdx.x / tn) * 128, n0 = (blockIdx.x % tn) * 128;

    f32x4 acc[4][4] = {};
    const int rowst = tid >> 3;          // 0..31
    const int colb = (tid & 7) * 16;     // byte offset within 128B row

    for (int k0 = 0; k0 < K; k0 += 64) {
#pragma unroll
        for (int i = 0; i < 4; ++i) {
            gload16((const char*)A + (((size_t)(m0 + i * 32 + rowst)) * K + k0) * 2 + colb,
                    (char*)As + i * 4096 + wid * 1024);
            gload16((const char*)Bt + (((size_t)(n0 + i * 32 + rowst)) * K + k0) * 2 + colb,
                    (char*)Bs + i * 4096 + wid * 1024);
        }
        __syncthreads();
#pragma unroll
        for (int kk = 0; kk < 2; ++kk) {
            s16x8 aF[4], bF[4];
#pragma unroll
            for (int m = 0; m < 4; ++m) aF[m] = *(const s16x8*)&As[(wr * 64 + m * 16 + li) * 64 + kk * 32 + g * 8];
#pragma unroll
            for (int n = 0; n < 4; ++n) bF[n] = *(const s16x8*)&Bs[(wc * 64 + n * 16 + li) * 64 + kk * 32 + g * 8];
#pragma unroll
            for (int m = 0; m < 4; ++m)
#pragma unroll
                for (int n = 0; n < 4; ++n)
                    acc[m][n] = MFMA(aF[m], bF[n], acc[m][n]);
        }
        __syncthreads();
    }

#pragma unroll
    for (int m = 0; m < 4; ++m)
#pragma unroll
        for (int n = 0; n < 4; ++n)
#pragma unroll
            for (int r = 0; r < 4; ++r) {
                size_t row = m0 + wr * 64 + m * 16 + g * 4 + r;
                size_t col = n0 + wc * 64 + n * 16 + li;
                size_t idx = row * N + col;
                float v = acc[m][n][r];
                if (mode == 0) {
                    ((float*)C)[idx] = v;
                } else if (mode == 1) {
                    ((u16*)C)[idx] = f2bf(v);
                } else if (mode == 2) {
                    float sg = 1.f / (1.f + __expf(-v));
                    ((u16*)C)[idx] = f2bf(v * sg);
                } else {
                    float h = bf2f(mul[idx]);
                    ((u16*)C)[idx] = f2bf(v * h);
                }
            }
}

// ---------------- RoPE in-place on q and k, [B,T,D] bf16, pairs (2i,2i+1) within each head
__global__ __launch_bounds__(256) void rope_qk(u16* __restrict__ q, u16* __restrict__ k,
                                               const float* __restrict__ fr) {
    size_t idx = (size_t)blockIdx.x * 256 + threadIdx.x; // over B*T*H*(HD/2)
    int i = (int)(idx & 31);
    int h = (int)((idx >> 5) & 15);
    size_t bt = idx >> 9;             // b*T + t
    int t = (int)(bt & (T_ - 1));
    float2 cs = ((const float2*)fr)[t * 32 + i];
    size_t off = bt * D_ + h * 64 + 2 * i;
    {
        u32* p = (u32*)(q + off);
        u32 w = *p;
        float a = bf2f((u16)(w & 0xffff)), b = bf2f((u16)(w >> 16));
        *p = (u32)f2bf(a * cs.x - b * cs.y) | ((u32)f2bf(a * cs.y + b * cs.x) << 16);
    }
    {
        u32* p = (u32*)(k + off);
        u32 w = *p;
        float a = bf2f((u16)(w & 0xffff)), b = bf2f((u16)(w >> 16));
        *p = (u32)f2bf(a * cs.x - b * cs.y) | ((u32)f2bf(a * cs.y + b * cs.x) << 16);
    }
}

// ---------------- V transpose: v[B,Tk,D] bf16 -> vT[B,H,HD,Tk] bf16
__global__ __launch_bounds__(256) void vtrans(const u16* __restrict__ v, u16* __restrict__ vT, int Tk) {
    __shared__ u16 tile[32][34];
    int bh = blockIdx.x;
    int t0 = blockIdx.y * 32, d0 = blockIdx.z * 32;
    int b = bh >> 4, h = bh & 15;
    int tid = threadIdx.x;
    int tx = tid & 31, ty = tid >> 5;
#pragma unroll
    for (int i = 0; i < 4; ++i)
        tile[ty + i * 8][tx] = v[((size_t)b * Tk + t0 + ty + i * 8) * D_ + h * 64 + d0 + tx];
    __syncthreads();
#pragma unroll
    for (int i = 0; i < 4; ++i)
        vT[((size_t)bh * 64 + d0 + ty + i * 8) * Tk + t0 + tx] = tile[tx][ty + i * 8];
}

// ---------------- fused flash attention: one wave = 16 q rows; 32 keys/iter
// q,k: [B,*,D] bf16 (head-major cols), vT: [B,H,HD,Tk], o: [B,Tq,D]
__global__ __launch_bounds__(256) void attn_fused(const u16* __restrict__ q, const u16* __restrict__ k,
                                                  const u16* __restrict__ vT, u16* __restrict__ o,
                                                  int Tq, int Tk, int causal) {
    const int lane = threadIdx.x & 63, wid = threadIdx.x >> 6;
    const int li = lane & 15, g = lane >> 4;
    const int tpb = (Tq / 16) / 4;
    const int bh = blockIdx.x / tpb;
    const int qt = (blockIdx.x % tpb) * 4 + wid;
    const int b = bh >> 4, h = bh & 15;
    const int q0 = qt * 16;

    const u16* qb = q + ((size_t)b * Tq + q0) * D_ + h * 64;
    const u16* kb = k + ((size_t)b * Tk) * D_ + h * 64;
    const u16* vb = vT + ((size_t)bh * 64) * Tk;

    __shared__ __align__(16) u16 Pl[4][16 * 32];
    u16* myP = Pl[wid];

    s16x8 aQ0 = *(const s16x8*)&qb[(size_t)li * D_ + g * 8];
    s16x8 aQ1 = *(const s16x8*)&qb[(size_t)li * D_ + 32 + g * 8];

    f32x4 oc[4] = {};
    float mr[4] = {-1e30f, -1e30f, -1e30f, -1e30f};
    float lr[4] = {0.f, 0.f, 0.f, 0.f};

    const int kend = causal ? (q0 + 16) : Tk;
    for (int ks = 0; ks < kend; ks += 32) {
        f32x4 s0 = {}, s1 = {};
        {
            s16x8 b0 = *(const s16x8*)&kb[(size_t)(ks + li) * D_ + g * 8];
            s16x8 b1 = *(const s16x8*)&kb[(size_t)(ks + li) * D_ + 32 + g * 8];
            s0 = MFMA(aQ0, b0, s0);
            s0 = MFMA(aQ1, b1, s0);
            s16x8 c0 = *(const s16x8*)&kb[(size_t)(ks + 16 + li) * D_ + g * 8];
            s16x8 c1 = *(const s16x8*)&kb[(size_t)(ks + 16 + li) * D_ + 32 + g * 8];
            s1 = MFMA(aQ0, c0, s1);
            s1 = MFMA(aQ1, c1, s1);
        }
#pragma unroll
        for (int r = 0; r < 4; ++r) {
            float v0 = s0[r] * 0.125f, v1 = s1[r] * 0.125f;
            if (causal) {
                int qr = q0 + g * 4 + r;
                if (ks + li > qr) v0 = -1e30f;
                if (ks + 16 + li > qr) v1 = -1e30f;
            }
            float tm = fmaxf(v0, v1);
            tm = fmaxf(tm, __shfl_xor(tm, 1));
            tm = fmaxf(tm, __shfl_xor(tm, 2));
            tm = fmaxf(tm, __shfl_xor(tm, 4));
            tm = fmaxf(tm, __shfl_xor(tm, 8));
            float mn = fmaxf(mr[r], tm);
            float sc = __expf(mr[r] - mn);
            mr[r] = mn;
            float p0 = __expf(v0 - mn), p1 = __expf(v1 - mn);
            float rs = p0 + p1;
            rs += __shfl_xor(rs, 1);
            rs += __shfl_xor(rs, 2);
            rs += __shfl_xor(rs, 4);
            rs += __shfl_xor(rs, 8);
            lr[r] = lr[r] * sc + rs;
#pragma unroll
            for (int c = 0; c < 4; ++c) oc[c][r] *= sc;
            myP[(g * 4 + r) * 32 + li] = f2bf(p0);
            myP[(g * 4 + r) * 32 + 16 + li] = f2bf(p1);
        }
        asm volatile("s_waitcnt lgkmcnt(0)" ::: "memory");
        __builtin_amdgcn_sched_barrier(0);
        s16x8 aP = *(const s16x8*)&myP[li * 32 + g * 8];
#pragma unroll
        for (int c = 0; c < 4; ++c) {
            s16x8 bV = *(const s16x8*)&vb[(size_t)(c * 16 + li) * Tk + ks + g * 8];
            oc[c] = MFMA(aP, bV, oc[c]);
        }
    }
    u16* ob = o + ((size_t)b * Tq + q0) * D_ + h * 64;
#pragma unroll
    for (int c = 0; c < 4; ++c)
#pragma unroll
        for (int r = 0; r < 4; ++r)
            ob[(size_t)(g * 4 + r) * D_ + c * 16 + li] = f2bf(oc[c][r] / lr[r]);
}

// ---------------- fused residual add + RMSNorm: y = (a+b)*rsqrt(mean((a+b)^2)+eps)*g
__global__ __launch_bounds__(256) void addnorm(const float* __restrict__ xa, const float* __restrict__ xb,
                                               const float* __restrict__ gg, float* __restrict__ fo,
                                               u16* __restrict__ bo) {
    int row = blockIdx.x, tid = threadIdx.x;
    float4 a = ((const float4*)(xa + (size_t)row * D_))[tid];
    float4 b = ((const float4*)(xb + (size_t)row * D_))[tid];
    float vx = a.x + b.x, vy = a.y + b.y, vz = a.z + b.z, vw = a.w + b.w;
    float ss = vx * vx + vy * vy + vz * vz + vw * vw;
    ss += __shfl_xor(ss, 1);
    ss += __shfl_xor(ss, 2);
    ss += __shfl_xor(ss, 4);
    ss += __shfl_xor(ss, 8);
    ss += __shfl_xor(ss, 16);
    ss += __shfl_xor(ss, 32);
    __shared__ float red[4];
    int lane = tid & 63, wid = tid >> 6;
    if (lane == 0) red[wid] = ss;
    __syncthreads();
    float tot = red[0] + red[1] + red[2] + red[3];
    float s = rsqrtf(tot * (1.0f / D_) + 1e-6f);
    float4 gv = ((const float4*)gg)[tid];
    float yx = vx * s * gv.x, yy = vy * s * gv.y, yz = vz * s * gv.z, yw = vw * s * gv.w;
    if (fo) {
        float4 o4; o4.x = yx; o4.y = yy; o4.z = yz; o4.w = yw;
        ((float4*)(fo + (size_t)row * D_))[tid] = o4;
    }
    if (bo) {
        u64 pk = (u64)f2bf(yx) | ((u64)f2bf(yy) << 16) | ((u64)f2bf(yz) << 32) | ((u64)f2bf(yw) << 48);
        ((u64*)(bo + (size_t)row * D_))[tid] = pk;
    }
}

extern "C" void kernel_launch(void* const* d_in, const int* in_sizes, int n_in,
                              void* d_out, int out_size, void* d_ws, size_t ws_size,
                              hipStream_t stream) {
    const float* x    = (const float*)d_in[0];
    const float* mem  = (const float*)d_in[1];
    const float* fr   = (const float*)d_in[2];
    const float* wsaq = (const float*)d_in[4];
    const float* wsak = (const float*)d_in[5];
    const float* wsav = (const float*)d_in[6];
    const float* wsao = (const float*)d_in[7];
    const float* wcaq = (const float*)d_in[8];
    const float* wcak = (const float*)d_in[9];
    const float* wcav = (const float*)d_in[10];
    const float* wcao = (const float*)d_in[11];
    const float* w1   = (const float*)d_in[12];
    const float* w3   = (const float*)d_in[13];
    const float* w2   = (const float*)d_in[14];
    const float* g_sa = (const float*)d_in[15];
    const float* g_ca = (const float*)d_in[16];
    const float* g_ff = (const float*)d_in[17];
    float* outF = (float*)d_out;

    char* p = (char*)d_ws;
    auto alloc = [&](size_t bytes) { char* r = p; p += (bytes + 255) & ~(size_t)255; return r; };
    const size_t DD2 = (size_t)1024 * 1024 * 2;
    u16* saqT = (u16*)alloc(DD2);
    u16* sakT = (u16*)alloc(DD2);
    u16* savT = (u16*)alloc(DD2);
    u16* saoT = (u16*)alloc(DD2);
    u16* caqT = (u16*)alloc(DD2);
    u16* cakT = (u16*)alloc(DD2);
    u16* cavT = (u16*)alloc(DD2);
    u16* caoT = (u16*)alloc(DD2);
    u16* w1T  = (u16*)alloc((size_t)HIDP_ * 1024 * 2);
    u16* w3T  = (u16*)alloc((size_t)HIDP_ * 1024 * 2);
    u16* w2T  = (u16*)alloc((size_t)1024 * HIDP_ * 2);
    u16* Ab   = (u16*)alloc((size_t)8192 * 1024 * 2);
    u16* memb = (u16*)alloc((size_t)2048 * 1024 * 2);
    u16* qb   = (u16*)alloc((size_t)8192 * 1024 * 2);
    u16* kb   = (u16*)alloc((size_t)8192 * 1024 * 2);
    u16* vb   = (u16*)alloc((size_t)8192 * 1024 * 2);
    u16* vtb  = (u16*)alloc((size_t)8192 * 1024 * 2);
    u16* ob   = (u16*)alloc((size_t)8192 * 1024 * 2);
    float* Pf = (float*)alloc((size_t)8192 * 1024 * 4);
    float* Rf = (float*)alloc((size_t)8192 * 1024 * 4);
    u16* Hb   = (u16*)alloc((size_t)8192 * HIDP_ * 2);

    dim3 blk(256);

    // weight prep
    wt_cast<<<dim3(32, 32), blk, 0, stream>>>(wsaq, saqT, 1024, 1024, 1024, 1024);
    wt_cast<<<dim3(32, 32), blk, 0, stream>>>(wsak, sakT, 1024, 1024, 1024, 1024);
    wt_cast<<<dim3(32, 32), blk, 0, stream>>>(wsav, savT, 1024, 1024, 1024, 1024);
    wt_cast<<<dim3(32, 32), blk, 0, stream>>>(wsao, saoT, 1024, 1024, 1024, 1024);
    wt_cast<<<dim3(32, 32), blk, 0, stream>>>(wcaq, caqT, 1024, 1024, 1024, 1024);
    wt_cast<<<dim3(32, 32), blk, 0, stream>>>(wcak, cakT, 1024, 1024, 1024, 1024);
    wt_cast<<<dim3(32, 32), blk, 0, stream>>>(wcav, cavT, 1024, 1024, 1024, 1024);
    wt_cast<<<dim3(32, 32), blk, 0, stream>>>(wcao, caoT, 1024, 1024, 1024, 1024);
    wt_cast<<<dim3(88, 32), blk, 0, stream>>>(w1, w1T, 1024, HID_, 1024, HIDP_);
    wt_cast<<<dim3(88, 32), blk, 0, stream>>>(w3, w3T, 1024, HID_, 1024, HIDP_);
    wt_cast<<<dim3(32, 88), blk, 0, stream>>>(w2, w2T, HID_, 1024, HIDP_, 1024);

    cast_bf16<<<8192, blk, 0, stream>>>(x, Ab, 2097152);
    cast_bf16<<<2048, blk, 0, stream>>>(mem, memb, 524288);

    // ---- self-attention
    gemm_bf16<<<512, blk, 0, stream>>>(Ab, saqT, qb, nullptr, 8192, 1024, 1024, 1);
    gemm_bf16<<<512, blk, 0, stream>>>(Ab, sakT, kb, nullptr, 8192, 1024, 1024, 1);
    gemm_bf16<<<512, blk, 0, stream>>>(Ab, savT, vb, nullptr, 8192, 1024, 1024, 1);
    rope_qk<<<16384, blk, 0, stream>>>(qb, kb, fr);
    vtrans<<<dim3(64, 64, 2), blk, 0, stream>>>(vb, vtb, 2048);
    attn_fused<<<2048, blk, 0, stream>>>(qb, kb, vtb, ob, 2048, 2048, 1);
    gemm_bf16<<<512, blk, 0, stream>>>(ob, saoT, Pf, nullptr, 8192, 1024, 1024, 0);
    addnorm<<<8192, blk, 0, stream>>>(x, Pf, g_sa, Rf, Ab);

    // ---- cross-attention
    gemm_bf16<<<512, blk, 0, stream>>>(Ab, caqT, qb, nullptr, 8192, 1024, 1024, 1);
    gemm_bf16<<<128, blk, 0, stream>>>(memb, cakT, kb, nullptr, 2048, 1024, 1024, 1);
    gemm_bf16<<<128, blk, 0, stream>>>(memb, cavT, vb, nullptr, 2048, 1024, 1024, 1);
    vtrans<<<dim3(64, 16, 2), blk, 0, stream>>>(vb, vtb, 512);
    attn_fused<<<2048, blk, 0, stream>>>(qb, kb, vtb, ob, 2048, 512, 0);
    gemm_bf16<<<512, blk, 0, stream>>>(ob, caoT, Pf, nullptr, 8192, 1024, 1024, 0);
    addnorm<<<8192, blk, 0, stream>>>(Rf, Pf, g_ca, Rf, Ab);

    // ---- FFN (SwiGLU)
    gemm_bf16<<<64 * 22, blk, 0, stream>>>(Ab, w1T, Hb, nullptr, 8192, HIDP_, 1024, 2);
    gemm_bf16<<<64 * 22, blk, 0, stream>>>(Ab, w3T, Hb, Hb, 8192, HIDP_, 1024, 3);
    gemm_bf16<<<512, blk, 0, stream>>>(Hb, w2T, Pf, nullptr, 8192, 1024, HIDP_, 0);
    addnorm<<<8192, blk, 0, stream>>>(Rf, Pf, g_ff, outF, nullptr);
}

// Round 2
// 1092.442 us; speedup vs baseline: 1.1957x; 1.1957x over previous
//
#include <hip/hip_runtime.h>
#include <hip/hip_bf16.h>

typedef __attribute__((ext_vector_type(8))) short s16x8;
typedef __attribute__((ext_vector_type(4))) float f32x4;
typedef unsigned short u16;
typedef unsigned int u32;
typedef unsigned long long u64;

#define MFMA(a,b,c) __builtin_amdgcn_mfma_f32_16x16x32_bf16(a,b,c,0,0,0)

constexpr int B_ = 4, T_ = 2048, TKV_ = 512, D_ = 1024, H_ = 16, HD_ = 64;
constexpr int HID_ = 2736, HIDP_ = 2816; // padded to 22*128

__device__ __forceinline__ float bf2f(u16 x) {
    union { float f; u32 u; } c; c.u = ((u32)x) << 16; return c.f;
}
__device__ __forceinline__ u16 f2bf(float f) {
    union { float f; u32 u; } c; c.f = f;
    u32 r = c.u + 0x7fffu + ((c.u >> 16) & 1u);
    return (u16)(r >> 16);
}

__device__ __forceinline__ void gload16(const void* g, void* l) {
    __builtin_amdgcn_global_load_lds(
        (const __attribute__((address_space(1))) u32*)g,
        (__attribute__((address_space(3))) u32*)l, 16, 0, 0);
}

// ---------------- weight transpose + cast:  W[K,N] f32 -> WT[Np,Kp] bf16 (zero-padded)
__global__ __launch_bounds__(256) void wt_cast(const float* __restrict__ W, u16* __restrict__ WT,
                                               int K, int N, int Kp, int Np) {
    __shared__ float t[32][33];
    int tid = threadIdx.x;
    int tx = tid & 31, ty = tid >> 5;
    int n0 = blockIdx.x * 32, k0 = blockIdx.y * 32;
#pragma unroll
    for (int i = 0; i < 4; ++i) {
        int kk = k0 + ty + i * 8, nn = n0 + tx;
        t[ty + i * 8][tx] = (kk < K && nn < N) ? W[(size_t)kk * N + nn] : 0.f;
    }
    __syncthreads();
#pragma unroll
    for (int i = 0; i < 4; ++i) {
        int nn = n0 + ty + i * 8, kk = k0 + tx;
        WT[(size_t)nn * Kp + kk] = f2bf(t[tx][ty + i * 8]);
    }
}

// ---------------- f32 -> bf16 cast (4 elems/thread)
__global__ __launch_bounds__(256) void cast_bf16(const float* __restrict__ in, u16* __restrict__ out, int n4) {
    int i = blockIdx.x * 256 + threadIdx.x;
    if (i >= n4) return;
    float4 v = ((const float4*)in)[i];
    u64 pk = (u64)f2bf(v.x) | ((u64)f2bf(v.y) << 16) | ((u64)f2bf(v.z) << 32) | ((u64)f2bf(v.w) << 48);
    ((u64*)out)[i] = pk;
}

// ---------------- GEMM: C[M,N] = A[M,K] @ Bt[N,K]^T, bf16 in, f32 acc.
// mode 0: f32 out; 1: bf16 out; 2: bf16 silu(out); 3: bf16 out*mul[idx]
__global__ __launch_bounds__(256) void gemm_bf16(const u16* __restrict__ A, const u16* __restrict__ Bt,
                                                 void* __restrict__ C, const u16* __restrict__ mul,
                                                 int M, int N, int K, int mode) {
    __shared__ __align__(16) u16 As[128 * 64];
    __shared__ __align__(16) u16 Bs[128 * 64];
    const int tid = threadIdx.x;
    const int lane = tid & 63, wid = tid >> 6;
    const int wr = wid >> 1, wc = wid & 1;
    const int li = lane & 15, g = lane >> 4;
    const int tn = N >> 7;
    const int m0 = (blockIdx.x / tn) * 128, n0 = (blockIdx.x % tn) * 128;

    f32x4 acc[4][4] = {};
    const int rowst = tid >> 3;          // 0..31
    const int colb = (tid & 7) * 16;     // byte offset within 128B row

    for (int k0 = 0; k0 < K; k0 += 64) {
#pragma unroll
        for (int i = 0; i < 4; ++i) {
            gload16((const char*)A + (((size_t)(m0 + i * 32 + rowst)) * K + k0) * 2 + colb,
                    (char*)As + i * 4096 + wid * 1024);
            gload16((const char*)Bt + (((size_t)(n0 + i * 32 + rowst)) * K + k0) * 2 + colb,
                    (char*)Bs + i * 4096 + wid * 1024);
        }
        __syncthreads();
#pragma unroll
        for (int kk = 0; kk < 2; ++kk) {
            s16x8 aF[4], bF[4];
#pragma unroll
            for (int m = 0; m < 4; ++m) aF[m] = *(const s16x8*)&As[(wr * 64 + m * 16 + li) * 64 + kk * 32 + g * 8];
#pragma unroll
            for (int n = 0; n < 4; ++n) bF[n] = *(const s16x8*)&Bs[(wc * 64 + n * 16 + li) * 64 + kk * 32 + g * 8];
#pragma unroll
            for (int m = 0; m < 4; ++m)
#pragma unroll
                for (int n = 0; n < 4; ++n)
                    acc[m][n] = MFMA(aF[m], bF[n], acc[m][n]);
        }
        __syncthreads();
    }

#pragma unroll
    for (int m = 0; m < 4; ++m)
#pragma unroll
        for (int n = 0; n < 4; ++n)
#pragma unroll
            for (int r = 0; r < 4; ++r) {
                size_t row = m0 + wr * 64 + m * 16 + g * 4 + r;
                size_t col = n0 + wc * 64 + n * 16 + li;
                size_t idx = row * N + col;
                float v = acc[m][n][r];
                if (mode == 0) {
                    ((float*)C)[idx] = v;
                } else if (mode == 1) {
                    ((u16*)C)[idx] = f2bf(v);
                } else if (mode == 2) {
                    float sg = 1.f / (1.f + __expf(-v));
                    ((u16*)C)[idx] = f2bf(v * sg);
                } else {
                    float h = bf2f(mul[idx]);
                    ((u16*)C)[idx] = f2bf(v * h);
                }
            }
}

// ---------------- RoPE in-place on q and k, [B,T,D] bf16, pairs (2i,2i+1) within each head
__global__ __launch_bounds__(256) void rope_qk(u16* __restrict__ q, u16* __restrict__ k,
                                               const float* __restrict__ fr) {
    size_t idx = (size_t)blockIdx.x * 256 + threadIdx.x; // over B*T*H*(HD/2)
    int i = (int)(idx & 31);
    int h = (int)((idx >> 5) & 15);
    size_t bt = idx >> 9;             // b*T + t
    int t = (int)(bt & (T_ - 1));
    float2 cs = ((const float2*)fr)[t * 32 + i];
    size_t off = bt * D_ + h * 64 + 2 * i;
    {
        u32* p = (u32*)(q + off);
        u32 w = *p;
        float a = bf2f((u16)(w & 0xffff)), b = bf2f((u16)(w >> 16));
        *p = (u32)f2bf(a * cs.x - b * cs.y) | ((u32)f2bf(a * cs.y + b * cs.x) << 16);
    }
    {
        u32* p = (u32*)(k + off);
        u32 w = *p;
        float a = bf2f((u16)(w & 0xffff)), b = bf2f((u16)(w >> 16));
        *p = (u32)f2bf(a * cs.x - b * cs.y) | ((u32)f2bf(a * cs.y + b * cs.x) << 16);
    }
}

// ---------------- V transpose: v[B,Tk,D] bf16 -> vT[B,H,HD,Tk] bf16
__global__ __launch_bounds__(256) void vtrans(const u16* __restrict__ v, u16* __restrict__ vT, int Tk) {
    __shared__ u16 tile[32][34];
    int bh = blockIdx.x;
    int t0 = blockIdx.y * 32, d0 = blockIdx.z * 32;
    int b = bh >> 4, h = bh & 15;
    int tid = threadIdx.x;
    int tx = tid & 31, ty = tid >> 5;
#pragma unroll
    for (int i = 0; i < 4; ++i)
        tile[ty + i * 8][tx] = v[((size_t)b * Tk + t0 + ty + i * 8) * D_ + h * 64 + d0 + tx];
    __syncthreads();
#pragma unroll
    for (int i = 0; i < 4; ++i)
        vT[((size_t)bh * 64 + d0 + ty + i * 8) * Tk + t0 + tx] = tile[tx][ty + i * 8];
}

// ---------------- attention tile: one wave, 16 q rows starting at q0, keys [0,kend)
// qh/kh: [*,D] bf16 bases offset to (b, h-col block); vh: vT base for bh; oh: out base
__device__ __forceinline__ void attn_tile(const u16* __restrict__ qh, const u16* __restrict__ kh,
                                          const u16* __restrict__ vh, u16* __restrict__ oh,
                                          u16* __restrict__ myP, int q0, int kend, int Tk,
                                          int causal, int li, int g) {
    const u16* qb = qh + (size_t)q0 * D_;

    s16x8 aQ0 = *(const s16x8*)&qb[(size_t)li * D_ + g * 8];
    s16x8 aQ1 = *(const s16x8*)&qb[(size_t)li * D_ + 32 + g * 8];

    f32x4 oc[4] = {};
    float mr[4] = {-1e30f, -1e30f, -1e30f, -1e30f};
    float lr[4] = {0.f, 0.f, 0.f, 0.f};

    for (int ks = 0; ks < kend; ks += 32) {
        f32x4 s0 = {}, s1 = {};
        {
            s16x8 b0 = *(const s16x8*)&kh[(size_t)(ks + li) * D_ + g * 8];
            s16x8 b1 = *(const s16x8*)&kh[(size_t)(ks + li) * D_ + 32 + g * 8];
            s0 = MFMA(aQ0, b0, s0);
            s0 = MFMA(aQ1, b1, s0);
            s16x8 c0 = *(const s16x8*)&kh[(size_t)(ks + 16 + li) * D_ + g * 8];
            s16x8 c1 = *(const s16x8*)&kh[(size_t)(ks + 16 + li) * D_ + 32 + g * 8];
            s1 = MFMA(aQ0, c0, s1);
            s1 = MFMA(aQ1, c1, s1);
        }
#pragma unroll
        for (int r = 0; r < 4; ++r) {
            float v0 = s0[r] * 0.125f, v1 = s1[r] * 0.125f;
            if (causal) {
                int qr = q0 + g * 4 + r;
                if (ks + li > qr) v0 = -1e30f;
                if (ks + 16 + li > qr) v1 = -1e30f;
            }
            float tm = fmaxf(v0, v1);
            tm = fmaxf(tm, __shfl_xor(tm, 1));
            tm = fmaxf(tm, __shfl_xor(tm, 2));
            tm = fmaxf(tm, __shfl_xor(tm, 4));
            tm = fmaxf(tm, __shfl_xor(tm, 8));
            float mn = fmaxf(mr[r], tm);
            float sc = __expf(mr[r] - mn);
            mr[r] = mn;
            float p0 = __expf(v0 - mn), p1 = __expf(v1 - mn);
            float rs = p0 + p1;
            rs += __shfl_xor(rs, 1);
            rs += __shfl_xor(rs, 2);
            rs += __shfl_xor(rs, 4);
            rs += __shfl_xor(rs, 8);
            lr[r] = lr[r] * sc + rs;
#pragma unroll
            for (int c = 0; c < 4; ++c) oc[c][r] *= sc;
            myP[(g * 4 + r) * 32 + li] = f2bf(p0);
            myP[(g * 4 + r) * 32 + 16 + li] = f2bf(p1);
        }
        asm volatile("s_waitcnt lgkmcnt(0)" ::: "memory");
        __builtin_amdgcn_sched_barrier(0);
        s16x8 aP = *(const s16x8*)&myP[li * 32 + g * 8];
#pragma unroll
        for (int c = 0; c < 4; ++c) {
            s16x8 bV = *(const s16x8*)&vh[(size_t)(c * 16 + li) * Tk + ks + g * 8];
            oc[c] = MFMA(aP, bV, oc[c]);
        }
    }
    u16* ob = oh + (size_t)q0 * D_;
#pragma unroll
    for (int c = 0; c < 4; ++c)
#pragma unroll
        for (int r = 0; r < 4; ++r)
            ob[(size_t)(g * 4 + r) * D_ + c * 16 + li] = f2bf(oc[c][r] / lr[r]);
}

// ---------------- causal self-attention, paired q-tiles for load balance.
// Each wave handles q-tile p AND q-tile (Nqt-1-p): uniform ~Nqt/2 iterations per wave.
__global__ __launch_bounds__(256) void attn_causal(const u16* __restrict__ q, const u16* __restrict__ k,
                                                   const u16* __restrict__ vT, u16* __restrict__ o,
                                                   int Tq, int Tk) {
    const int lane = threadIdx.x & 63, wid = threadIdx.x >> 6;
    const int li = lane & 15, g = lane >> 4;
    const int nqt = Tq / 16;              // 128 q-tiles per (b,h)
    const int ppb = (nqt / 2) / 4;        // pairs per block = 16
    const int bh = blockIdx.x / ppb;
    const int p = (blockIdx.x % ppb) * 4 + wid;
    const int b = bh >> 4, h = bh & 15;

    const u16* qh = q + ((size_t)b * Tq) * D_ + h * 64;
    const u16* kh = k + ((size_t)b * Tk) * D_ + h * 64;
    const u16* vh = vT + ((size_t)bh * 64) * Tk;
    u16* oh = o + ((size_t)b * Tq) * D_ + h * 64;

    __shared__ __align__(16) u16 Pl[4][16 * 32];
    u16* myP = Pl[wid];

    const int qtA = p, qtB = nqt - 1 - p;
    attn_tile(qh, kh, vh, oh, myP, qtA * 16, qtA * 16 + 16, Tk, 1, li, g);
    attn_tile(qh, kh, vh, oh, myP, qtB * 16, qtB * 16 + 16, Tk, 1, li, g);
}

// ---------------- non-causal cross-attention: one wave = one 16-row q tile (uniform work)
__global__ __launch_bounds__(256) void attn_plain(const u16* __restrict__ q, const u16* __restrict__ k,
                                                  const u16* __restrict__ vT, u16* __restrict__ o,
                                                  int Tq, int Tk) {
    const int lane = threadIdx.x & 63, wid = threadIdx.x >> 6;
    const int li = lane & 15, g = lane >> 4;
    const int tpb = (Tq / 16) / 4;
    const int bh = blockIdx.x / tpb;
    const int qt = (blockIdx.x % tpb) * 4 + wid;
    const int b = bh >> 4, h = bh & 15;

    const u16* qh = q + ((size_t)b * Tq) * D_ + h * 64;
    const u16* kh = k + ((size_t)b * Tk) * D_ + h * 64;
    const u16* vh = vT + ((size_t)bh * 64) * Tk;
    u16* oh = o + ((size_t)b * Tq) * D_ + h * 64;

    __shared__ __align__(16) u16 Pl[4][16 * 32];
    u16* myP = Pl[wid];

    attn_tile(qh, kh, vh, oh, myP, qt * 16, Tk, Tk, 0, li, g);
}

// ---------------- fused residual add + RMSNorm: y = (a+b)*rsqrt(mean((a+b)^2)+eps)*g
__global__ __launch_bounds__(256) void addnorm(const float* __restrict__ xa, const float* __restrict__ xb,
                                               const float* __restrict__ gg, float* __restrict__ fo,
                                               u16* __restrict__ bo) {
    int row = blockIdx.x, tid = threadIdx.x;
    float4 a = ((const float4*)(xa + (size_t)row * D_))[tid];
    float4 b = ((const float4*)(xb + (size_t)row * D_))[tid];
    float vx = a.x + b.x, vy = a.y + b.y, vz = a.z + b.z, vw = a.w + b.w;
    float ss = vx * vx + vy * vy + vz * vz + vw * vw;
    ss += __shfl_xor(ss, 1);
    ss += __shfl_xor(ss, 2);
    ss += __shfl_xor(ss, 4);
    ss += __shfl_xor(ss, 8);
    ss += __shfl_xor(ss, 16);
    ss += __shfl_xor(ss, 32);
    __shared__ float red[4];
    int lane = tid & 63, wid = tid >> 6;
    if (lane == 0) red[wid] = ss;
    __syncthreads();
    float tot = red[0] + red[1] + red[2] + red[3];
    float s = rsqrtf(tot * (1.0f / D_) + 1e-6f);
    float4 gv = ((const float4*)gg)[tid];
    float yx = vx * s * gv.x, yy = vy * s * gv.y, yz = vz * s * gv.z, yw = vw * s * gv.w;
    if (fo) {
        float4 o4; o4.x = yx; o4.y = yy; o4.z = yz; o4.w = yw;
        ((float4*)(fo + (size_t)row * D_))[tid] = o4;
    }
    if (bo) {
        u64 pk = (u64)f2bf(yx) | ((u64)f2bf(yy) << 16) | ((u64)f2bf(yz) << 32) | ((u64)f2bf(yw) << 48);
        ((u64*)(bo + (size_t)row * D_))[tid] = pk;
    }
}

extern "C" void kernel_launch(void* const* d_in, const int* in_sizes, int n_in,
                              void* d_out, int out_size, void* d_ws, size_t ws_size,
                              hipStream_t stream) {
    const float* x    = (const float*)d_in[0];
    const float* mem  = (const float*)d_in[1];
    const float* fr   = (const float*)d_in[2];
    const float* wsaq = (const float*)d_in[4];
    const float* wsak = (const float*)d_in[5];
    const float* wsav = (const float*)d_in[6];
    const float* wsao = (const float*)d_in[7];
    const float* wcaq = (const float*)d_in[8];
    const float* wcak = (const float*)d_in[9];
    const float* wcav = (const float*)d_in[10];
    const float* wcao = (const float*)d_in[11];
    const float* w1   = (const float*)d_in[12];
    const float* w3   = (const float*)d_in[13];
    const float* w2   = (const float*)d_in[14];
    const float* g_sa = (const float*)d_in[15];
    const float* g_ca = (const float*)d_in[16];
    const float* g_ff = (const float*)d_in[17];
    float* outF = (float*)d_out;

    char* p = (char*)d_ws;
    auto alloc = [&](size_t bytes) { char* r = p; p += (bytes + 255) & ~(size_t)255; return r; };
    const size_t DD2 = (size_t)1024 * 1024 * 2;
    u16* saqT = (u16*)alloc(DD2);
    u16* sakT = (u16*)alloc(DD2);
    u16* savT = (u16*)alloc(DD2);
    u16* saoT = (u16*)alloc(DD2);
    u16* caqT = (u16*)alloc(DD2);
    u16* cakT = (u16*)alloc(DD2);
    u16* cavT = (u16*)alloc(DD2);
    u16* caoT = (u16*)alloc(DD2);
    u16* w1T  = (u16*)alloc((size_t)HIDP_ * 1024 * 2);
    u16* w3T  = (u16*)alloc((size_t)HIDP_ * 1024 * 2);
    u16* w2T  = (u16*)alloc((size_t)1024 * HIDP_ * 2);
    u16* Ab   = (u16*)alloc((size_t)8192 * 1024 * 2);
    u16* memb = (u16*)alloc((size_t)2048 * 1024 * 2);
    u16* qb   = (u16*)alloc((size_t)8192 * 1024 * 2);
    u16* kb   = (u16*)alloc((size_t)8192 * 1024 * 2);
    u16* vb   = (u16*)alloc((size_t)8192 * 1024 * 2);
    u16* vtb  = (u16*)alloc((size_t)8192 * 1024 * 2);
    u16* ob   = (u16*)alloc((size_t)8192 * 1024 * 2);
    float* Pf = (float*)alloc((size_t)8192 * 1024 * 4);
    float* Rf = (float*)alloc((size_t)8192 * 1024 * 4);
    u16* Hb   = (u16*)alloc((size_t)8192 * HIDP_ * 2);

    dim3 blk(256);

    // weight prep
    wt_cast<<<dim3(32, 32), blk, 0, stream>>>(wsaq, saqT, 1024, 1024, 1024, 1024);
    wt_cast<<<dim3(32, 32), blk, 0, stream>>>(wsak, sakT, 1024, 1024, 1024, 1024);
    wt_cast<<<dim3(32, 32), blk, 0, stream>>>(wsav, savT, 1024, 1024, 1024, 1024);
    wt_cast<<<dim3(32, 32), blk, 0, stream>>>(wsao, saoT, 1024, 1024, 1024, 1024);
    wt_cast<<<dim3(32, 32), blk, 0, stream>>>(wcaq, caqT, 1024, 1024, 1024, 1024);
    wt_cast<<<dim3(32, 32), blk, 0, stream>>>(wcak, cakT, 1024, 1024, 1024, 1024);
    wt_cast<<<dim3(32, 32), blk, 0, stream>>>(wcav, cavT, 1024, 1024, 1024, 1024);
    wt_cast<<<dim3(32, 32), blk, 0, stream>>>(wcao, caoT, 1024, 1024, 1024, 1024);
    wt_cast<<<dim3(88, 32), blk, 0, stream>>>(w1, w1T, 1024, HID_, 1024, HIDP_);
    wt_cast<<<dim3(88, 32), blk, 0, stream>>>(w3, w3T, 1024, HID_, 1024, HIDP_);
    wt_cast<<<dim3(32, 88), blk, 0, stream>>>(w2, w2T, HID_, 1024, HIDP_, 1024);

    cast_bf16<<<8192, blk, 0, stream>>>(x, Ab, 2097152);
    cast_bf16<<<2048, blk, 0, stream>>>(mem, memb, 524288);

    // ---- self-attention
    gemm_bf16<<<512, blk, 0, stream>>>(Ab, saqT, qb, nullptr, 8192, 1024, 1024, 1);
    gemm_bf16<<<512, blk, 0, stream>>>(Ab, sakT, kb, nullptr, 8192, 1024, 1024, 1);
    gemm_bf16<<<512, blk, 0, stream>>>(Ab, savT, vb, nullptr, 8192, 1024, 1024, 1);
    rope_qk<<<16384, blk, 0, stream>>>(qb, kb, fr);
    vtrans<<<dim3(64, 64, 2), blk, 0, stream>>>(vb, vtb, 2048);
    attn_causal<<<1024, blk, 0, stream>>>(qb, kb, vtb, ob, 2048, 2048);
    gemm_bf16<<<512, blk, 0, stream>>>(ob, saoT, Pf, nullptr, 8192, 1024, 1024, 0);
    addnorm<<<8192, blk, 0, stream>>>(x, Pf, g_sa, Rf, Ab);

    // ---- cross-attention
    gemm_bf16<<<512, blk, 0, stream>>>(Ab, caqT, qb, nullptr, 8192, 1024, 1024, 1);
    gemm_bf16<<<128, blk, 0, stream>>>(memb, cakT, kb, nullptr, 2048, 1024, 1024, 1);
    gemm_bf16<<<128, blk, 0, stream>>>(memb, cavT, vb, nullptr, 2048, 1024, 1024, 1);
    vtrans<<<dim3(64, 16, 2), blk, 0, stream>>>(vb, vtb, 512);
    attn_plain<<<2048, blk, 0, stream>>>(qb, kb, vtb, ob, 2048, 512);
    gemm_bf16<<<512, blk, 0, stream>>>(ob, caoT, Pf, nullptr, 8192, 1024, 1024, 0);
    addnorm<<<8192, blk, 0, stream>>>(Rf, Pf, g_ca, Rf, Ab);

    // ---- FFN (SwiGLU)
    gemm_bf16<<<64 * 22, blk, 0, stream>>>(Ab, w1T, Hb, nullptr, 8192, HIDP_, 1024, 2);
    gemm_bf16<<<64 * 22, blk, 0, stream>>>(Ab, w3T, Hb, Hb, 8192, HIDP_, 1024, 3);
    gemm_bf16<<<512, blk, 0, stream>>>(Hb, w2T, Pf, nullptr, 8192, 1024, HIDP_, 0);
    addnorm<<<8192, blk, 0, stream>>>(Rf, Pf, g_ff, outF, nullptr);
}

// Round 3
// 956.683 us; speedup vs baseline: 1.3654x; 1.1419x over previous
//
#include <hip/hip_runtime.h>
#include <hip/hip_bf16.h>

typedef __attribute__((ext_vector_type(8))) short s16x8;
typedef __attribute__((ext_vector_type(4))) float f32x4;
typedef __attribute__((ext_vector_type(16))) float f32x16;
typedef unsigned short u16;
typedef unsigned int u32;
typedef unsigned long long u64;

#define MFMA(a,b,c) __builtin_amdgcn_mfma_f32_16x16x32_bf16(a,b,c,0,0,0)
#define MFMA32(a,b,c) __builtin_amdgcn_mfma_f32_32x32x16_bf16(a,b,c,0,0,0)

constexpr int B_ = 4, T_ = 2048, TKV_ = 512, D_ = 1024, H_ = 16, HD_ = 64;
constexpr int HID_ = 2736, HIDP_ = 2816; // padded to 22*128

__device__ __forceinline__ float bf2f(u16 x) {
    union { float f; u32 u; } c; c.u = ((u32)x) << 16; return c.f;
}
__device__ __forceinline__ u16 f2bf(float f) {
    union { float f; u32 u; } c; c.f = f;
    u32 r = c.u + 0x7fffu + ((c.u >> 16) & 1u);
    return (u16)(r >> 16);
}

__device__ __forceinline__ void gload16(const void* g, void* l) {
    __builtin_amdgcn_global_load_lds(
        (const __attribute__((address_space(1))) u32*)g,
        (__attribute__((address_space(3))) u32*)l, 16, 0, 0);
}

// ---------------- weight transpose + cast:  W[K,N] f32 -> WT[Np,Kp] bf16 (zero-padded)
__global__ __launch_bounds__(256) void wt_cast(const float* __restrict__ W, u16* __restrict__ WT,
                                               int K, int N, int Kp, int Np) {
    __shared__ float t[32][33];
    int tid = threadIdx.x;
    int tx = tid & 31, ty = tid >> 5;
    int n0 = blockIdx.x * 32, k0 = blockIdx.y * 32;
#pragma unroll
    for (int i = 0; i < 4; ++i) {
        int kk = k0 + ty + i * 8, nn = n0 + tx;
        t[ty + i * 8][tx] = (kk < K && nn < N) ? W[(size_t)kk * N + nn] : 0.f;
    }
    __syncthreads();
#pragma unroll
    for (int i = 0; i < 4; ++i) {
        int nn = n0 + ty + i * 8, kk = k0 + tx;
        WT[(size_t)nn * Kp + kk] = f2bf(t[tx][ty + i * 8]);
    }
}

// ---------------- f32 -> bf16 cast (4 elems/thread)
__global__ __launch_bounds__(256) void cast_bf16(const float* __restrict__ in, u16* __restrict__ out, int n4) {
    int i = blockIdx.x * 256 + threadIdx.x;
    if (i >= n4) return;
    float4 v = ((const float4*)in)[i];
    u64 pk = (u64)f2bf(v.x) | ((u64)f2bf(v.y) << 16) | ((u64)f2bf(v.z) << 32) | ((u64)f2bf(v.w) << 48);
    ((u64*)out)[i] = pk;
}

// ---------------- GEMM: C[M,N] = A[M,K] @ Bt[N,K]^T, bf16 in, f32 acc.
// mode 0: f32 out; 1: bf16 out; 2: bf16 silu(out); 3: bf16 out*mul[idx]; 4: bf16 out*0.125
__global__ __launch_bounds__(256) void gemm_bf16(const u16* __restrict__ A, const u16* __restrict__ Bt,
                                                 void* __restrict__ C, const u16* __restrict__ mul,
                                                 int M, int N, int K, int mode) {
    __shared__ __align__(16) u16 As[128 * 64];
    __shared__ __align__(16) u16 Bs[128 * 64];
    const int tid = threadIdx.x;
    const int lane = tid & 63, wid = tid >> 6;
    const int wr = wid >> 1, wc = wid & 1;
    const int li = lane & 15, g = lane >> 4;
    const int tn = N >> 7;
    const int m0 = (blockIdx.x / tn) * 128, n0 = (blockIdx.x % tn) * 128;

    f32x4 acc[4][4] = {};
    const int rowst = tid >> 3;          // 0..31
    const int colb = (tid & 7) * 16;     // byte offset within 128B row

    for (int k0 = 0; k0 < K; k0 += 64) {
#pragma unroll
        for (int i = 0; i < 4; ++i) {
            gload16((const char*)A + (((size_t)(m0 + i * 32 + rowst)) * K + k0) * 2 + colb,
                    (char*)As + i * 4096 + wid * 1024);
            gload16((const char*)Bt + (((size_t)(n0 + i * 32 + rowst)) * K + k0) * 2 + colb,
                    (char*)Bs + i * 4096 + wid * 1024);
        }
        __syncthreads();
#pragma unroll
        for (int kk = 0; kk < 2; ++kk) {
            s16x8 aF[4], bF[4];
#pragma unroll
            for (int m = 0; m < 4; ++m) aF[m] = *(const s16x8*)&As[(wr * 64 + m * 16 + li) * 64 + kk * 32 + g * 8];
#pragma unroll
            for (int n = 0; n < 4; ++n) bF[n] = *(const s16x8*)&Bs[(wc * 64 + n * 16 + li) * 64 + kk * 32 + g * 8];
#pragma unroll
            for (int m = 0; m < 4; ++m)
#pragma unroll
                for (int n = 0; n < 4; ++n)
                    acc[m][n] = MFMA(aF[m], bF[n], acc[m][n]);
        }
        __syncthreads();
    }

#pragma unroll
    for (int m = 0; m < 4; ++m)
#pragma unroll
        for (int n = 0; n < 4; ++n)
#pragma unroll
            for (int r = 0; r < 4; ++r) {
                size_t row = m0 + wr * 64 + m * 16 + g * 4 + r;
                size_t col = n0 + wc * 64 + n * 16 + li;
                size_t idx = row * N + col;
                float v = acc[m][n][r];
                if (mode == 0) {
                    ((float*)C)[idx] = v;
                } else if (mode == 1) {
                    ((u16*)C)[idx] = f2bf(v);
                } else if (mode == 2) {
                    float sg = 1.f / (1.f + __expf(-v));
                    ((u16*)C)[idx] = f2bf(v * sg);
                } else if (mode == 3) {
                    float h = bf2f(mul[idx]);
                    ((u16*)C)[idx] = f2bf(v * h);
                } else {
                    ((u16*)C)[idx] = f2bf(v * 0.125f);
                }
            }
}

// ---------------- RoPE in-place on q and k; q additionally scaled by 1/sqrt(HD)=0.125
__global__ __launch_bounds__(256) void rope_qk(u16* __restrict__ q, u16* __restrict__ k,
                                               const float* __restrict__ fr) {
    size_t idx = (size_t)blockIdx.x * 256 + threadIdx.x; // over B*T*H*(HD/2)
    int i = (int)(idx & 31);
    int h = (int)((idx >> 5) & 15);
    size_t bt = idx >> 9;             // b*T + t
    int t = (int)(bt & (T_ - 1));
    float2 cs = ((const float2*)fr)[t * 32 + i];
    size_t off = bt * D_ + h * 64 + 2 * i;
    {
        u32* p = (u32*)(q + off);
        u32 w = *p;
        float a = bf2f((u16)(w & 0xffff)), b = bf2f((u16)(w >> 16));
        *p = (u32)f2bf((a * cs.x - b * cs.y) * 0.125f) | ((u32)f2bf((a * cs.y + b * cs.x) * 0.125f) << 16);
    }
    {
        u32* p = (u32*)(k + off);
        u32 w = *p;
        float a = bf2f((u16)(w & 0xffff)), b = bf2f((u16)(w >> 16));
        *p = (u32)f2bf(a * cs.x - b * cs.y) | ((u32)f2bf(a * cs.y + b * cs.x) << 16);
    }
}

// ---------------- V transpose: v[B,Tk,D] bf16 -> vT[B,H,HD,Tk] bf16
__global__ __launch_bounds__(256) void vtrans(const u16* __restrict__ v, u16* __restrict__ vT, int Tk) {
    __shared__ u16 tile[32][34];
    int bh = blockIdx.x;
    int t0 = blockIdx.y * 32, d0 = blockIdx.z * 32;
    int b = bh >> 4, h = bh & 15;
    int tid = threadIdx.x;
    int tx = tid & 31, ty = tid >> 5;
#pragma unroll
    for (int i = 0; i < 4; ++i)
        tile[ty + i * 8][tx] = v[((size_t)b * Tk + t0 + ty + i * 8) * D_ + h * 64 + d0 + tx];
    __syncthreads();
#pragma unroll
    for (int i = 0; i < 4; ++i)
        vT[((size_t)bh * 64 + d0 + ty + i * 8) * Tk + t0 + tx] = tile[tx][ty + i * 8];
}

// ---------------- swapped-QK^T 32x32 attention tile: one wave = 32 q rows.
// S^T = mfma32(K, Q): lane owns q-col (lq=lane&31); its 16 regs hold k rows
// k(r) = (r&3)+8*(r>>2)+4*hi (hi=lane>>5); lane^32 holds the other 16 k's of same q.
// Q pre-scaled by 0.125. O^T = V^T * P^T via vT[hd][t] layout.
__device__ __forceinline__ void attn32(const u16* __restrict__ qh, const u16* __restrict__ kh,
                                       const u16* __restrict__ vh, u16* __restrict__ oh,
                                       int q0, int nkb, int Tk, int causal, int lq, int hi) {
    const u16* qb = qh + (size_t)(q0 + lq) * D_;
    s16x8 qf[4];
#pragma unroll
    for (int c = 0; c < 4; ++c) qf[c] = *(const s16x8*)&qb[c * 16 + hi * 8];

    f32x16 o0 = {}, o1 = {};
    float mr = -1e30f, lr = 0.f;

    for (int kb = 0; kb < nkb; ++kb) {
        const int ks = kb * 32;
        f32x16 s = {};
        const u16* kp = kh + (size_t)(ks + lq) * D_ + hi * 8;
#pragma unroll
        for (int c = 0; c < 4; ++c) {
            s16x8 kf = *(const s16x8*)&kp[c * 16];
            s = MFMA32(kf, qf[c], s);
        }
        if (causal && kb == nkb - 1) {
#pragma unroll
            for (int r = 0; r < 16; ++r) {
                int kl = (r & 3) + 8 * (r >> 2) + 4 * hi;
                if (kl > lq) s[r] = -1e30f;
            }
        }
        // row max (lane-local tree + one cross-half exchange)
        float bm = fmaxf(fmaxf(fmaxf(s[0], s[1]), fmaxf(s[2], s[3])),
                         fmaxf(fmaxf(s[4], s[5]), fmaxf(s[6], s[7])));
        float bm2 = fmaxf(fmaxf(fmaxf(s[8], s[9]), fmaxf(s[10], s[11])),
                          fmaxf(fmaxf(s[12], s[13]), fmaxf(s[14], s[15])));
        bm = fmaxf(bm, bm2);
        bm = fmaxf(bm, __shfl_xor(bm, 32));
        float mn = fmaxf(mr, bm);
        float sc = __expf(mr - mn);
        mr = mn;
        float p[16];
        float rs = 0.f;
#pragma unroll
        for (int r = 0; r < 16; ++r) { p[r] = __expf(s[r] - mn); rs += p[r]; }
        rs += __shfl_xor(rs, 32);
        lr = lr * sc + rs;
#pragma unroll
        for (int r = 0; r < 16; ++r) { o0[r] *= sc; o1[r] *= sc; }

        // pack P to bf16 words; redistribute across lane halves for the B-fragment
        u32 pk[8];
#pragma unroll
        for (int i = 0; i < 8; ++i)
            pk[i] = (u32)f2bf(p[2 * i]) | ((u32)f2bf(p[2 * i + 1]) << 16);
        u32 e1 = __shfl_xor(hi ? pk[0] : pk[2], 32);
        u32 e2 = __shfl_xor(hi ? pk[1] : pk[3], 32);
        u32 e3 = __shfl_xor(hi ? pk[4] : pk[6], 32);
        u32 e4 = __shfl_xor(hi ? pk[5] : pk[7], 32);
        union { s16x8 v; u32 w[4]; } pf0, pf1;
        pf0.w[0] = hi ? e1 : pk[0];
        pf0.w[1] = hi ? e2 : pk[1];
        pf0.w[2] = hi ? pk[2] : e1;
        pf0.w[3] = hi ? pk[3] : e2;
        pf1.w[0] = hi ? e3 : pk[4];
        pf1.w[1] = hi ? e4 : pk[5];
        pf1.w[2] = hi ? pk[6] : e3;
        pf1.w[3] = hi ? pk[7] : e4;

        const u16* v0 = vh + (size_t)lq * Tk + ks + hi * 8;
        const u16* v1 = vh + (size_t)(32 + lq) * Tk + ks + hi * 8;
        o0 = MFMA32(*(const s16x8*)&v0[0],  pf0.v, o0);
        o0 = MFMA32(*(const s16x8*)&v0[16], pf1.v, o0);
        o1 = MFMA32(*(const s16x8*)&v1[0],  pf0.v, o1);
        o1 = MFMA32(*(const s16x8*)&v1[16], pf1.v, o1);
    }

    float inv = 1.f / lr;
    u16* ob = oh + (size_t)(q0 + lq) * D_;
#pragma unroll
    for (int r = 0; r < 16; ++r) {
        int hd = (r & 3) + 8 * (r >> 2) + 4 * hi;
        ob[hd] = f2bf(o0[r] * inv);
        ob[hd + 32] = f2bf(o1[r] * inv);
    }
}

// ---------------- causal self-attention: paired 32-row q-tiles, uniform 65 iters/wave
__global__ __launch_bounds__(256) void attn_causal32(const u16* __restrict__ q, const u16* __restrict__ k,
                                                     const u16* __restrict__ vT, u16* __restrict__ o,
                                                     int Tq, int Tk) {
    const int lane = threadIdx.x & 63, wid = threadIdx.x >> 6;
    const int lq = lane & 31, hi = lane >> 5;
    const int ntile = Tq / 32;            // 64
    const int ppb = (ntile / 2) / 4;      // 8 pairs per block
    const int bh = blockIdx.x / ppb;
    const int p = (blockIdx.x % ppb) * 4 + wid;
    const int b = bh >> 4, h = bh & 15;

    const u16* qh = q + ((size_t)b * Tq) * D_ + h * 64;
    const u16* kh = k + ((size_t)b * Tk) * D_ + h * 64;
    const u16* vh = vT + ((size_t)bh * 64) * Tk;
    u16* oh = o + ((size_t)b * Tq) * D_ + h * 64;

    const int tA = p, tB = ntile - 1 - p;
    attn32(qh, kh, vh, oh, tA * 32, tA + 1, Tk, 1, lq, hi);
    attn32(qh, kh, vh, oh, tB * 32, tB + 1, Tk, 1, lq, hi);
}

// ---------------- non-causal cross-attention: one wave per 32-row q-tile
__global__ __launch_bounds__(256) void attn_plain32(const u16* __restrict__ q, const u16* __restrict__ k,
                                                    const u16* __restrict__ vT, u16* __restrict__ o,
                                                    int Tq, int Tk) {
    const int lane = threadIdx.x & 63, wid = threadIdx.x >> 6;
    const int lq = lane & 31, hi = lane >> 5;
    const int tpb = (Tq / 32) / 4;        // 16 tiles per block
    const int bh = blockIdx.x / tpb;
    const int qt = (blockIdx.x % tpb) * 4 + wid;
    const int b = bh >> 4, h = bh & 15;

    const u16* qh = q + ((size_t)b * Tq) * D_ + h * 64;
    const u16* kh = k + ((size_t)b * Tk) * D_ + h * 64;
    const u16* vh = vT + ((size_t)bh * 64) * Tk;
    u16* oh = o + ((size_t)b * Tq) * D_ + h * 64;

    attn32(qh, kh, vh, oh, qt * 32, Tk / 32, Tk, 0, lq, hi);
}

// ---------------- fused residual add + RMSNorm: y = (a+b)*rsqrt(mean((a+b)^2)+eps)*g
__global__ __launch_bounds__(256) void addnorm(const float* __restrict__ xa, const float* __restrict__ xb,
                                               const float* __restrict__ gg, float* __restrict__ fo,
                                               u16* __restrict__ bo) {
    int row = blockIdx.x, tid = threadIdx.x;
    float4 a = ((const float4*)(xa + (size_t)row * D_))[tid];
    float4 b = ((const float4*)(xb + (size_t)row * D_))[tid];
    float vx = a.x + b.x, vy = a.y + b.y, vz = a.z + b.z, vw = a.w + b.w;
    float ss = vx * vx + vy * vy + vz * vz + vw * vw;
    ss += __shfl_xor(ss, 1);
    ss += __shfl_xor(ss, 2);
    ss += __shfl_xor(ss, 4);
    ss += __shfl_xor(ss, 8);
    ss += __shfl_xor(ss, 16);
    ss += __shfl_xor(ss, 32);
    __shared__ float red[4];
    int lane = tid & 63, wid = tid >> 6;
    if (lane == 0) red[wid] = ss;
    __syncthreads();
    float tot = red[0] + red[1] + red[2] + red[3];
    float s = rsqrtf(tot * (1.0f / D_) + 1e-6f);
    float4 gv = ((const float4*)gg)[tid];
    float yx = vx * s * gv.x, yy = vy * s * gv.y, yz = vz * s * gv.z, yw = vw * s * gv.w;
    if (fo) {
        float4 o4; o4.x = yx; o4.y = yy; o4.z = yz; o4.w = yw;
        ((float4*)(fo + (size_t)row * D_))[tid] = o4;
    }
    if (bo) {
        u64 pk = (u64)f2bf(yx) | ((u64)f2bf(yy) << 16) | ((u64)f2bf(yz) << 32) | ((u64)f2bf(yw) << 48);
        ((u64*)(bo + (size_t)row * D_))[tid] = pk;
    }
}

extern "C" void kernel_launch(void* const* d_in, const int* in_sizes, int n_in,
                              void* d_out, int out_size, void* d_ws, size_t ws_size,
                              hipStream_t stream) {
    const float* x    = (const float*)d_in[0];
    const float* mem  = (const float*)d_in[1];
    const float* fr   = (const float*)d_in[2];
    const float* wsaq = (const float*)d_in[4];
    const float* wsak = (const float*)d_in[5];
    const float* wsav = (const float*)d_in[6];
    const float* wsao = (const float*)d_in[7];
    const float* wcaq = (const float*)d_in[8];
    const float* wcak = (const float*)d_in[9];
    const float* wcav = (const float*)d_in[10];
    const float* wcao = (const float*)d_in[11];
    const float* w1   = (const float*)d_in[12];
    const float* w3   = (const float*)d_in[13];
    const float* w2   = (const float*)d_in[14];
    const float* g_sa = (const float*)d_in[15];
    const float* g_ca = (const float*)d_in[16];
    const float* g_ff = (const float*)d_in[17];
    float* outF = (float*)d_out;

    char* p = (char*)d_ws;
    auto alloc = [&](size_t bytes) { char* r = p; p += (bytes + 255) & ~(size_t)255; return r; };
    const size_t DD2 = (size_t)1024 * 1024 * 2;
    u16* saqT = (u16*)alloc(DD2);
    u16* sakT = (u16*)alloc(DD2);
    u16* savT = (u16*)alloc(DD2);
    u16* saoT = (u16*)alloc(DD2);
    u16* caqT = (u16*)alloc(DD2);
    u16* cakT = (u16*)alloc(DD2);
    u16* cavT = (u16*)alloc(DD2);
    u16* caoT = (u16*)alloc(DD2);
    u16* w1T  = (u16*)alloc((size_t)HIDP_ * 1024 * 2);
    u16* w3T  = (u16*)alloc((size_t)HIDP_ * 1024 * 2);
    u16* w2T  = (u16*)alloc((size_t)1024 * HIDP_ * 2);
    u16* Ab   = (u16*)alloc((size_t)8192 * 1024 * 2);
    u16* memb = (u16*)alloc((size_t)2048 * 1024 * 2);
    u16* qb   = (u16*)alloc((size_t)8192 * 1024 * 2);
    u16* kb   = (u16*)alloc((size_t)8192 * 1024 * 2);
    u16* vb   = (u16*)alloc((size_t)8192 * 1024 * 2);
    u16* vtb  = (u16*)alloc((size_t)8192 * 1024 * 2);
    u16* ob   = (u16*)alloc((size_t)8192 * 1024 * 2);
    float* Pf = (float*)alloc((size_t)8192 * 1024 * 4);
    float* Rf = (float*)alloc((size_t)8192 * 1024 * 4);
    u16* Hb   = (u16*)alloc((size_t)8192 * HIDP_ * 2);

    dim3 blk(256);

    // weight prep
    wt_cast<<<dim3(32, 32), blk, 0, stream>>>(wsaq, saqT, 1024, 1024, 1024, 1024);
    wt_cast<<<dim3(32, 32), blk, 0, stream>>>(wsak, sakT, 1024, 1024, 1024, 1024);
    wt_cast<<<dim3(32, 32), blk, 0, stream>>>(wsav, savT, 1024, 1024, 1024, 1024);
    wt_cast<<<dim3(32, 32), blk, 0, stream>>>(wsao, saoT, 1024, 1024, 1024, 1024);
    wt_cast<<<dim3(32, 32), blk, 0, stream>>>(wcaq, caqT, 1024, 1024, 1024, 1024);
    wt_cast<<<dim3(32, 32), blk, 0, stream>>>(wcak, cakT, 1024, 1024, 1024, 1024);
    wt_cast<<<dim3(32, 32), blk, 0, stream>>>(wcav, cavT, 1024, 1024, 1024, 1024);
    wt_cast<<<dim3(32, 32), blk, 0, stream>>>(wcao, caoT, 1024, 1024, 1024, 1024);
    wt_cast<<<dim3(88, 32), blk, 0, stream>>>(w1, w1T, 1024, HID_, 1024, HIDP_);
    wt_cast<<<dim3(88, 32), blk, 0, stream>>>(w3, w3T, 1024, HID_, 1024, HIDP_);
    wt_cast<<<dim3(32, 88), blk, 0, stream>>>(w2, w2T, HID_, 1024, HIDP_, 1024);

    cast_bf16<<<8192, blk, 0, stream>>>(x, Ab, 2097152);
    cast_bf16<<<2048, blk, 0, stream>>>(mem, memb, 524288);

    // ---- self-attention
    gemm_bf16<<<512, blk, 0, stream>>>(Ab, saqT, qb, nullptr, 8192, 1024, 1024, 1);
    gemm_bf16<<<512, blk, 0, stream>>>(Ab, sakT, kb, nullptr, 8192, 1024, 1024, 1);
    gemm_bf16<<<512, blk, 0, stream>>>(Ab, savT, vb, nullptr, 8192, 1024, 1024, 1);
    rope_qk<<<16384, blk, 0, stream>>>(qb, kb, fr);
    vtrans<<<dim3(64, 64, 2), blk, 0, stream>>>(vb, vtb, 2048);
    attn_causal32<<<512, blk, 0, stream>>>(qb, kb, vtb, ob, 2048, 2048);
    gemm_bf16<<<512, blk, 0, stream>>>(ob, saoT, Pf, nullptr, 8192, 1024, 1024, 0);
    addnorm<<<8192, blk, 0, stream>>>(x, Pf, g_sa, Rf, Ab);

    // ---- cross-attention (q scaled by 0.125 in GEMM epilogue, mode 4)
    gemm_bf16<<<512, blk, 0, stream>>>(Ab, caqT, qb, nullptr, 8192, 1024, 1024, 4);
    gemm_bf16<<<128, blk, 0, stream>>>(memb, cakT, kb, nullptr, 2048, 1024, 1024, 1);
    gemm_bf16<<<128, blk, 0, stream>>>(memb, cavT, vb, nullptr, 2048, 1024, 1024, 1);
    vtrans<<<dim3(64, 16, 2), blk, 0, stream>>>(vb, vtb, 512);
    attn_plain32<<<1024, blk, 0, stream>>>(qb, kb, vtb, ob, 2048, 512);
    gemm_bf16<<<512, blk, 0, stream>>>(ob, caoT, Pf, nullptr, 8192, 1024, 1024, 0);
    addnorm<<<8192, blk, 0, stream>>>(Rf, Pf, g_ca, Rf, Ab);

    // ---- FFN (SwiGLU)
    gemm_bf16<<<64 * 22, blk, 0, stream>>>(Ab, w1T, Hb, nullptr, 8192, HIDP_, 1024, 2);
    gemm_bf16<<<64 * 22, blk, 0, stream>>>(Ab, w3T, Hb, Hb, 8192, HIDP_, 1024, 3);
    gemm_bf16<<<512, blk, 0, stream>>>(Hb, w2T, Pf, nullptr, 8192, 1024, HIDP_, 0);
    addnorm<<<8192, blk, 0, stream>>>(Rf, Pf, g_ff, outF, nullptr);
}

// Round 4
// 945.100 us; speedup vs baseline: 1.3821x; 1.0123x over previous
//
#include <hip/hip_runtime.h>
#include <hip/hip_bf16.h>

typedef __attribute__((ext_vector_type(8))) short s16x8;
typedef __attribute__((ext_vector_type(4))) float f32x4;
typedef __attribute__((ext_vector_type(16))) float f32x16;
typedef unsigned short u16;
typedef unsigned int u32;
typedef unsigned long long u64;

#define MFMA(a,b,c) __builtin_amdgcn_mfma_f32_16x16x32_bf16(a,b,c,0,0,0)
#define MFMA32(a,b,c) __builtin_amdgcn_mfma_f32_32x32x16_bf16(a,b,c,0,0,0)

constexpr int B_ = 4, T_ = 2048, TKV_ = 512, D_ = 1024, H_ = 16, HD_ = 64;
constexpr int HID_ = 2736, HIDP_ = 2816; // padded to 22*128

__device__ __forceinline__ float bf2f(u16 x) {
    union { float f; u32 u; } c; c.u = ((u32)x) << 16; return c.f;
}
__device__ __forceinline__ u16 f2bf(float f) {
    union { float f; u32 u; } c; c.f = f;
    u32 r = c.u + 0x7fffu + ((c.u >> 16) & 1u);
    return (u16)(r >> 16);
}

__device__ __forceinline__ void gload16(const void* g, void* l) {
    __builtin_amdgcn_global_load_lds(
        (const __attribute__((address_space(1))) u32*)g,
        (__attribute__((address_space(3))) u32*)l, 16, 0, 0);
}

// ---------------- weight transpose + cast:  W[K,N] f32 -> WT[Np,Kp] bf16 (zero-padded)
__global__ __launch_bounds__(256) void wt_cast(const float* __restrict__ W, u16* __restrict__ WT,
                                               int K, int N, int Kp, int Np) {
    __shared__ float t[32][33];
    int tid = threadIdx.x;
    int tx = tid & 31, ty = tid >> 5;
    int n0 = blockIdx.x * 32, k0 = blockIdx.y * 32;
#pragma unroll
    for (int i = 0; i < 4; ++i) {
        int kk = k0 + ty + i * 8, nn = n0 + tx;
        t[ty + i * 8][tx] = (kk < K && nn < N) ? W[(size_t)kk * N + nn] : 0.f;
    }
    __syncthreads();
#pragma unroll
    for (int i = 0; i < 4; ++i) {
        int nn = n0 + ty + i * 8, kk = k0 + tx;
        WT[(size_t)nn * Kp + kk] = f2bf(t[tx][ty + i * 8]);
    }
}

// ---------------- f32 -> bf16 cast (4 elems/thread)
__global__ __launch_bounds__(256) void cast_bf16(const float* __restrict__ in, u16* __restrict__ out, int n4) {
    int i = blockIdx.x * 256 + threadIdx.x;
    if (i >= n4) return;
    float4 v = ((const float4*)in)[i];
    u64 pk = (u64)f2bf(v.x) | ((u64)f2bf(v.y) << 16) | ((u64)f2bf(v.z) << 32) | ((u64)f2bf(v.w) << 48);
    ((u64*)out)[i] = pk;
}

// ---------------- GEMM: C[M,N] = A[M,K] @ Bt[N,K]^T, bf16 in, f32 acc.
// 2-phase prefetch double-buffer (catalog T3-minimum): stage tile t+1 into
// buf^1 BEFORE computing buf; single vmcnt(0)+barrier per K-step (iteration end).
// mode 0: f32 out; 1: bf16 out; 2: bf16 silu(out); 3: bf16 out*mul[idx]; 4: bf16 out*0.125
__global__ __launch_bounds__(256) void gemm_bf16(const u16* __restrict__ A, const u16* __restrict__ Bt,
                                                 void* __restrict__ C, const u16* __restrict__ mul,
                                                 int M, int N, int K, int mode, int nwg) {
    __shared__ __align__(16) u16 As[2][128 * 64];
    __shared__ __align__(16) u16 Bs[2][128 * 64];
    const int tid = threadIdx.x;
    const int lane = tid & 63, wid = tid >> 6;
    const int wr = wid >> 1, wc = wid & 1;
    const int li = lane & 15, g = lane >> 4;

    // bijective XCD swizzle (all grids are multiples of 8)
    int bid = (int)blockIdx.x;
    bid = (bid & 7) * (nwg >> 3) + (bid >> 3);

    const int tn = N >> 7;
    const int m0 = (bid / tn) * 128, n0 = (bid % tn) * 128;

    const int rowst = tid >> 3;          // 0..31
    const int colb = (tid & 7) * 16;     // byte offset within 128B row
    const char* ga = (const char*)A + ((size_t)(m0 + rowst) * K) * 2 + colb;
    const char* gb = (const char*)Bt + ((size_t)(n0 + rowst) * K) * 2 + colb;
    const size_t rstride = (size_t)32 * K * 2;   // 32 rows in bytes

    f32x4 acc[4][4] = {};
    const int nt = K >> 6;

    // prologue: stage tile 0 into buffer 0
#pragma unroll
    for (int i = 0; i < 4; ++i) {
        gload16(ga + i * rstride, (char*)As[0] + i * 4096 + wid * 1024);
        gload16(gb + i * rstride, (char*)Bs[0] + i * 4096 + wid * 1024);
    }
    __syncthreads();   // compiler emits vmcnt(0) drain before barrier

    int cur = 0;
    for (int t = 0; t < nt; ++t) {
        // stage tile t+1 into the other buffer (issue-first, overlap with MFMA below)
        if (t + 1 < nt) {
            const char* gan = ga + (size_t)(t + 1) * 128;
            const char* gbn = gb + (size_t)(t + 1) * 128;
#pragma unroll
            for (int i = 0; i < 4; ++i) {
                gload16(gan + i * rstride, (char*)As[cur ^ 1] + i * 4096 + wid * 1024);
                gload16(gbn + i * rstride, (char*)Bs[cur ^ 1] + i * 4096 + wid * 1024);
            }
        }
        // compute tile t from buf[cur]
#pragma unroll
        for (int kk = 0; kk < 2; ++kk) {
            s16x8 aF[4], bF[4];
#pragma unroll
            for (int m = 0; m < 4; ++m) aF[m] = *(const s16x8*)&As[cur][(wr * 64 + m * 16 + li) * 64 + kk * 32 + g * 8];
#pragma unroll
            for (int n = 0; n < 4; ++n) bF[n] = *(const s16x8*)&Bs[cur][(wc * 64 + n * 16 + li) * 64 + kk * 32 + g * 8];
#pragma unroll
            for (int m = 0; m < 4; ++m)
#pragma unroll
                for (int n = 0; n < 4; ++n)
                    acc[m][n] = MFMA(aF[m], bF[n], acc[m][n]);
        }
        __syncthreads();   // vmcnt(0): tile t+1 landed; lgkm: all reads of buf[cur] done
        cur ^= 1;
    }

#pragma unroll
    for (int m = 0; m < 4; ++m)
#pragma unroll
        for (int n = 0; n < 4; ++n)
#pragma unroll
            for (int r = 0; r < 4; ++r) {
                size_t row = m0 + wr * 64 + m * 16 + g * 4 + r;
                size_t col = n0 + wc * 64 + n * 16 + li;
                size_t idx = row * N + col;
                float v = acc[m][n][r];
                if (mode == 0) {
                    ((float*)C)[idx] = v;
                } else if (mode == 1) {
                    ((u16*)C)[idx] = f2bf(v);
                } else if (mode == 2) {
                    float sg = 1.f / (1.f + __expf(-v));
                    ((u16*)C)[idx] = f2bf(v * sg);
                } else if (mode == 3) {
                    float h = bf2f(mul[idx]);
                    ((u16*)C)[idx] = f2bf(v * h);
                } else {
                    ((u16*)C)[idx] = f2bf(v * 0.125f);
                }
            }
}

// ---------------- RoPE in-place on q and k; q additionally scaled by 1/sqrt(HD)=0.125
__global__ __launch_bounds__(256) void rope_qk(u16* __restrict__ q, u16* __restrict__ k,
                                               const float* __restrict__ fr) {
    size_t idx = (size_t)blockIdx.x * 256 + threadIdx.x; // over B*T*H*(HD/2)
    int i = (int)(idx & 31);
    int h = (int)((idx >> 5) & 15);
    size_t bt = idx >> 9;             // b*T + t
    int t = (int)(bt & (T_ - 1));
    float2 cs = ((const float2*)fr)[t * 32 + i];
    size_t off = bt * D_ + h * 64 + 2 * i;
    {
        u32* p = (u32*)(q + off);
        u32 w = *p;
        float a = bf2f((u16)(w & 0xffff)), b = bf2f((u16)(w >> 16));
        *p = (u32)f2bf((a * cs.x - b * cs.y) * 0.125f) | ((u32)f2bf((a * cs.y + b * cs.x) * 0.125f) << 16);
    }
    {
        u32* p = (u32*)(k + off);
        u32 w = *p;
        float a = bf2f((u16)(w & 0xffff)), b = bf2f((u16)(w >> 16));
        *p = (u32)f2bf(a * cs.x - b * cs.y) | ((u32)f2bf(a * cs.y + b * cs.x) << 16);
    }
}

// ---------------- V transpose: v[B,Tk,D] bf16 -> vT[B,H,HD,Tk] bf16
__global__ __launch_bounds__(256) void vtrans(const u16* __restrict__ v, u16* __restrict__ vT, int Tk) {
    __shared__ u16 tile[32][34];
    int bh = blockIdx.x;
    int t0 = blockIdx.y * 32, d0 = blockIdx.z * 32;
    int b = bh >> 4, h = bh & 15;
    int tid = threadIdx.x;
    int tx = tid & 31, ty = tid >> 5;
#pragma unroll
    for (int i = 0; i < 4; ++i)
        tile[ty + i * 8][tx] = v[((size_t)b * Tk + t0 + ty + i * 8) * D_ + h * 64 + d0 + tx];
    __syncthreads();
#pragma unroll
    for (int i = 0; i < 4; ++i)
        vT[((size_t)bh * 64 + d0 + ty + i * 8) * Tk + t0 + tx] = tile[tx][ty + i * 8];
}

// ---------------- swapped-QK^T 32x32 attention tile: one wave = 32 q rows.
// S^T = mfma32(K, Q): lane owns q-col (lq=lane&31); its 16 regs hold k rows
// k(r) = (r&3)+8*(r>>2)+4*hi (hi=lane>>5); lane^32 holds the other 16 k's of same q.
// Q pre-scaled by 0.125. O^T = V^T * P^T via vT[hd][t] layout.
__device__ __forceinline__ void attn32(const u16* __restrict__ qh, const u16* __restrict__ kh,
                                       const u16* __restrict__ vh, u16* __restrict__ oh,
                                       int q0, int nkb, int Tk, int causal, int lq, int hi) {
    const u16* qb = qh + (size_t)(q0 + lq) * D_;
    s16x8 qf[4];
#pragma unroll
    for (int c = 0; c < 4; ++c) qf[c] = *(const s16x8*)&qb[c * 16 + hi * 8];

    f32x16 o0 = {}, o1 = {};
    float mr = -1e30f, lr = 0.f;

    for (int kb = 0; kb < nkb; ++kb) {
        const int ks = kb * 32;
        f32x16 s = {};
        const u16* kp = kh + (size_t)(ks + lq) * D_ + hi * 8;
#pragma unroll
        for (int c = 0; c < 4; ++c) {
            s16x8 kf = *(const s16x8*)&kp[c * 16];
            s = MFMA32(kf, qf[c], s);
        }
        if (causal && kb == nkb - 1) {
#pragma unroll
            for (int r = 0; r < 16; ++r) {
                int kl = (r & 3) + 8 * (r >> 2) + 4 * hi;
                if (kl > lq) s[r] = -1e30f;
            }
        }
        // row max (lane-local tree + one cross-half exchange)
        float bm = fmaxf(fmaxf(fmaxf(s[0], s[1]), fmaxf(s[2], s[3])),
                         fmaxf(fmaxf(s[4], s[5]), fmaxf(s[6], s[7])));
        float bm2 = fmaxf(fmaxf(fmaxf(s[8], s[9]), fmaxf(s[10], s[11])),
                          fmaxf(fmaxf(s[12], s[13]), fmaxf(s[14], s[15])));
        bm = fmaxf(bm, bm2);
        bm = fmaxf(bm, __shfl_xor(bm, 32));
        float mn = fmaxf(mr, bm);
        float sc = __expf(mr - mn);
        mr = mn;
        float p[16];
        float rs = 0.f;
#pragma unroll
        for (int r = 0; r < 16; ++r) { p[r] = __expf(s[r] - mn); rs += p[r]; }
        rs += __shfl_xor(rs, 32);
        lr = lr * sc + rs;
#pragma unroll
        for (int r = 0; r < 16; ++r) { o0[r] *= sc; o1[r] *= sc; }

        // pack P to bf16 words; redistribute across lane halves for the B-fragment
        u32 pk[8];
#pragma unroll
        for (int i = 0; i < 8; ++i)
            pk[i] = (u32)f2bf(p[2 * i]) | ((u32)f2bf(p[2 * i + 1]) << 16);
        u32 e1 = __shfl_xor(hi ? pk[0] : pk[2], 32);
        u32 e2 = __shfl_xor(hi ? pk[1] : pk[3], 32);
        u32 e3 = __shfl_xor(hi ? pk[4] : pk[6], 32);
        u32 e4 = __shfl_xor(hi ? pk[5] : pk[7], 32);
        union { s16x8 v; u32 w[4]; } pf0, pf1;
        pf0.w[0] = hi ? e1 : pk[0];
        pf0.w[1] = hi ? e2 : pk[1];
        pf0.w[2] = hi ? pk[2] : e1;
        pf0.w[3] = hi ? pk[3] : e2;
        pf1.w[0] = hi ? e3 : pk[4];
        pf1.w[1] = hi ? e4 : pk[5];
        pf1.w[2] = hi ? pk[6] : e3;
        pf1.w[3] = hi ? pk[7] : e4;

        const u16* v0 = vh + (size_t)lq * Tk + ks + hi * 8;
        const u16* v1 = vh + (size_t)(32 + lq) * Tk + ks + hi * 8;
        o0 = MFMA32(*(const s16x8*)&v0[0],  pf0.v, o0);
        o0 = MFMA32(*(const s16x8*)&v0[16], pf1.v, o0);
        o1 = MFMA32(*(const s16x8*)&v1[0],  pf0.v, o1);
        o1 = MFMA32(*(const s16x8*)&v1[16], pf1.v, o1);
    }

    float inv = 1.f / lr;
    u16* ob = oh + (size_t)(q0 + lq) * D_;
#pragma unroll
    for (int r = 0; r < 16; ++r) {
        int hd = (r & 3) + 8 * (r >> 2) + 4 * hi;
        ob[hd] = f2bf(o0[r] * inv);
        ob[hd + 32] = f2bf(o1[r] * inv);
    }
}

// ---------------- causal self-attention: paired 32-row q-tiles, uniform 65 iters/wave
__global__ __launch_bounds__(256) void attn_causal32(const u16* __restrict__ q, const u16* __restrict__ k,
                                                     const u16* __restrict__ vT, u16* __restrict__ o,
                                                     int Tq, int Tk) {
    const int lane = threadIdx.x & 63, wid = threadIdx.x >> 6;
    const int lq = lane & 31, hi = lane >> 5;
    const int ntile = Tq / 32;            // 64
    const int ppb = (ntile / 2) / 4;      // 8 pairs per block
    const int bh = blockIdx.x / ppb;
    const int p = (blockIdx.x % ppb) * 4 + wid;
    const int b = bh >> 4, h = bh & 15;

    const u16* qh = q + ((size_t)b * Tq) * D_ + h * 64;
    const u16* kh = k + ((size_t)b * Tk) * D_ + h * 64;
    const u16* vh = vT + ((size_t)bh * 64) * Tk;
    u16* oh = o + ((size_t)b * Tq) * D_ + h * 64;

    const int tA = p, tB = ntile - 1 - p;
    attn32(qh, kh, vh, oh, tA * 32, tA + 1, Tk, 1, lq, hi);
    attn32(qh, kh, vh, oh, tB * 32, tB + 1, Tk, 1, lq, hi);
}

// ---------------- non-causal cross-attention: one wave per 32-row q-tile
__global__ __launch_bounds__(256) void attn_plain32(const u16* __restrict__ q, const u16* __restrict__ k,
                                                    const u16* __restrict__ vT, u16* __restrict__ o,
                                                    int Tq, int Tk) {
    const int lane = threadIdx.x & 63, wid = threadIdx.x >> 6;
    const int lq = lane & 31, hi = lane >> 5;
    const int tpb = (Tq / 32) / 4;        // 16 tiles per block
    const int bh = blockIdx.x / tpb;
    const int qt = (blockIdx.x % tpb) * 4 + wid;
    const int b = bh >> 4, h = bh & 15;

    const u16* qh = q + ((size_t)b * Tq) * D_ + h * 64;
    const u16* kh = k + ((size_t)b * Tk) * D_ + h * 64;
    const u16* vh = vT + ((size_t)bh * 64) * Tk;
    u16* oh = o + ((size_t)b * Tq) * D_ + h * 64;

    attn32(qh, kh, vh, oh, qt * 32, Tk / 32, Tk, 0, lq, hi);
}

// ---------------- fused residual add + RMSNorm: y = (a+b)*rsqrt(mean((a+b)^2)+eps)*g
__global__ __launch_bounds__(256) void addnorm(const float* __restrict__ xa, const float* __restrict__ xb,
                                               const float* __restrict__ gg, float* __restrict__ fo,
                                               u16* __restrict__ bo) {
    int row = blockIdx.x, tid = threadIdx.x;
    float4 a = ((const float4*)(xa + (size_t)row * D_))[tid];
    float4 b = ((const float4*)(xb + (size_t)row * D_))[tid];
    float vx = a.x + b.x, vy = a.y + b.y, vz = a.z + b.z, vw = a.w + b.w;
    float ss = vx * vx + vy * vy + vz * vz + vw * vw;
    ss += __shfl_xor(ss, 1);
    ss += __shfl_xor(ss, 2);
    ss += __shfl_xor(ss, 4);
    ss += __shfl_xor(ss, 8);
    ss += __shfl_xor(ss, 16);
    ss += __shfl_xor(ss, 32);
    __shared__ float red[4];
    int lane = tid & 63, wid = tid >> 6;
    if (lane == 0) red[wid] = ss;
    __syncthreads();
    float tot = red[0] + red[1] + red[2] + red[3];
    float s = rsqrtf(tot * (1.0f / D_) + 1e-6f);
    float4 gv = ((const float4*)gg)[tid];
    float yx = vx * s * gv.x, yy = vy * s * gv.y, yz = vz * s * gv.z, yw = vw * s * gv.w;
    if (fo) {
        float4 o4; o4.x = yx; o4.y = yy; o4.z = yz; o4.w = yw;
        ((float4*)(fo + (size_t)row * D_))[tid] = o4;
    }
    if (bo) {
        u64 pk = (u64)f2bf(yx) | ((u64)f2bf(yy) << 16) | ((u64)f2bf(yz) << 32) | ((u64)f2bf(yw) << 48);
        ((u64*)(bo + (size_t)row * D_))[tid] = pk;
    }
}

extern "C" void kernel_launch(void* const* d_in, const int* in_sizes, int n_in,
                              void* d_out, int out_size, void* d_ws, size_t ws_size,
                              hipStream_t stream) {
    const float* x    = (const float*)d_in[0];
    const float* mem  = (const float*)d_in[1];
    const float* fr   = (const float*)d_in[2];
    const float* wsaq = (const float*)d_in[4];
    const float* wsak = (const float*)d_in[5];
    const float* wsav = (const float*)d_in[6];
    const float* wsao = (const float*)d_in[7];
    const float* wcaq = (const float*)d_in[8];
    const float* wcak = (const float*)d_in[9];
    const float* wcav = (const float*)d_in[10];
    const float* wcao = (const float*)d_in[11];
    const float* w1   = (const float*)d_in[12];
    const float* w3   = (const float*)d_in[13];
    const float* w2   = (const float*)d_in[14];
    const float* g_sa = (const float*)d_in[15];
    const float* g_ca = (const float*)d_in[16];
    const float* g_ff = (const float*)d_in[17];
    float* outF = (float*)d_out;

    char* p = (char*)d_ws;
    auto alloc = [&](size_t bytes) { char* r = p; p += (bytes + 255) & ~(size_t)255; return r; };
    const size_t DD2 = (size_t)1024 * 1024 * 2;
    u16* saqT = (u16*)alloc(DD2);
    u16* sakT = (u16*)alloc(DD2);
    u16* savT = (u16*)alloc(DD2);
    u16* saoT = (u16*)alloc(DD2);
    u16* caqT = (u16*)alloc(DD2);
    u16* cakT = (u16*)alloc(DD2);
    u16* cavT = (u16*)alloc(DD2);
    u16* caoT = (u16*)alloc(DD2);
    u16* w1T  = (u16*)alloc((size_t)HIDP_ * 1024 * 2);
    u16* w3T  = (u16*)alloc((size_t)HIDP_ * 1024 * 2);
    u16* w2T  = (u16*)alloc((size_t)1024 * HIDP_ * 2);
    u16* Ab   = (u16*)alloc((size_t)8192 * 1024 * 2);
    u16* memb = (u16*)alloc((size_t)2048 * 1024 * 2);
    u16* qb   = (u16*)alloc((size_t)8192 * 1024 * 2);
    u16* kb   = (u16*)alloc((size_t)8192 * 1024 * 2);
    u16* vb   = (u16*)alloc((size_t)8192 * 1024 * 2);
    u16* vtb  = (u16*)alloc((size_t)8192 * 1024 * 2);
    u16* ob   = (u16*)alloc((size_t)8192 * 1024 * 2);
    float* Pf = (float*)alloc((size_t)8192 * 1024 * 4);
    float* Rf = (float*)alloc((size_t)8192 * 1024 * 4);
    u16* Hb   = (u16*)alloc((size_t)8192 * HIDP_ * 2);

    dim3 blk(256);

    // weight prep
    wt_cast<<<dim3(32, 32), blk, 0, stream>>>(wsaq, saqT, 1024, 1024, 1024, 1024);
    wt_cast<<<dim3(32, 32), blk, 0, stream>>>(wsak, sakT, 1024, 1024, 1024, 1024);
    wt_cast<<<dim3(32, 32), blk, 0, stream>>>(wsav, savT, 1024, 1024, 1024, 1024);
    wt_cast<<<dim3(32, 32), blk, 0, stream>>>(wsao, saoT, 1024, 1024, 1024, 1024);
    wt_cast<<<dim3(32, 32), blk, 0, stream>>>(wcaq, caqT, 1024, 1024, 1024, 1024);
    wt_cast<<<dim3(32, 32), blk, 0, stream>>>(wcak, cakT, 1024, 1024, 1024, 1024);
    wt_cast<<<dim3(32, 32), blk, 0, stream>>>(wcav, cavT, 1024, 1024, 1024, 1024);
    wt_cast<<<dim3(32, 32), blk, 0, stream>>>(wcao, caoT, 1024, 1024, 1024, 1024);
    wt_cast<<<dim3(88, 32), blk, 0, stream>>>(w1, w1T, 1024, HID_, 1024, HIDP_);
    wt_cast<<<dim3(88, 32), blk, 0, stream>>>(w3, w3T, 1024, HID_, 1024, HIDP_);
    wt_cast<<<dim3(32, 88), blk, 0, stream>>>(w2, w2T, HID_, 1024, HIDP_, 1024);

    cast_bf16<<<8192, blk, 0, stream>>>(x, Ab, 2097152);
    cast_bf16<<<2048, blk, 0, stream>>>(mem, memb, 524288);

    // ---- self-attention
    gemm_bf16<<<512, blk, 0, stream>>>(Ab, saqT, qb, nullptr, 8192, 1024, 1024, 1, 512);
    gemm_bf16<<<512, blk, 0, stream>>>(Ab, sakT, kb, nullptr, 8192, 1024, 1024, 1, 512);
    gemm_bf16<<<512, blk, 0, stream>>>(Ab, savT, vb, nullptr, 8192, 1024, 1024, 1, 512);
    rope_qk<<<16384, blk, 0, stream>>>(qb, kb, fr);
    vtrans<<<dim3(64, 64, 2), blk, 0, stream>>>(vb, vtb, 2048);
    attn_causal32<<<512, blk, 0, stream>>>(qb, kb, vtb, ob, 2048, 2048);
    gemm_bf16<<<512, blk, 0, stream>>>(ob, saoT, Pf, nullptr, 8192, 1024, 1024, 0, 512);
    addnorm<<<8192, blk, 0, stream>>>(x, Pf, g_sa, Rf, Ab);

    // ---- cross-attention (q scaled by 0.125 in GEMM epilogue, mode 4)
    gemm_bf16<<<512, blk, 0, stream>>>(Ab, caqT, qb, nullptr, 8192, 1024, 1024, 4, 512);
    gemm_bf16<<<128, blk, 0, stream>>>(memb, cakT, kb, nullptr, 2048, 1024, 1024, 1, 128);
    gemm_bf16<<<128, blk, 0, stream>>>(memb, cavT, vb, nullptr, 2048, 1024, 1024, 1, 128);
    vtrans<<<dim3(64, 16, 2), blk, 0, stream>>>(vb, vtb, 512);
    attn_plain32<<<1024, blk, 0, stream>>>(qb, kb, vtb, ob, 2048, 512);
    gemm_bf16<<<512, blk, 0, stream>>>(ob, caoT, Pf, nullptr, 8192, 1024, 1024, 0, 512);
    addnorm<<<8192, blk, 0, stream>>>(Rf, Pf, g_ca, Rf, Ab);

    // ---- FFN (SwiGLU)
    gemm_bf16<<<64 * 22, blk, 0, stream>>>(Ab, w1T, Hb, nullptr, 8192, HIDP_, 1024, 2, 64 * 22);
    gemm_bf16<<<64 * 22, blk, 0, stream>>>(Ab, w3T, Hb, Hb, 8192, HIDP_, 1024, 3, 64 * 22);
    gemm_bf16<<<512, blk, 0, stream>>>(Hb, w2T, Pf, nullptr, 8192, 1024, HIDP_, 0, 512);
    addnorm<<<8192, blk, 0, stream>>>(Rf, Pf, g_ff, outF, nullptr);
}